// Round 9
// baseline (72.053 us; speedup 1.0000x reference)
//
#include <hip/hip_runtime.h>
#include <hip/hip_bf16.h>

typedef __attribute__((ext_vector_type(8))) short short8;
typedef __attribute__((ext_vector_type(4))) float f32x4;

#define N_ENS 16
#define D_IN 784
#define D_HID 128
#define D_OUT 10
#define NKT 25            // K tiles of 32 (784 padded to 800)
#define TILE_B 8192       // 128 cols x 32 k x 2B (bf16), fragment-packed + swizzled
#define WS_B1 204800      // NKT*8192
#define WS_W2 205312      // + 128*4   (w2 stored [10][128] f32)
#define WS_B2 210432      // + 1280*4

#define A_STRIDE 1616     // bytes per A-LDS row (808 bf16)
#define B_BASE 51712      // A region = 32*1616 = 51712 B
#define SB __builtin_amdgcn_sched_barrier(0)

// RNE float->bf16 (inputs are finite)
__device__ __forceinline__ unsigned short f2bf(float f) {
  unsigned int u = __float_as_uint(f);
  return (unsigned short)((u + 0x7FFFu + ((u >> 16) & 1u)) >> 16);
}

__device__ __forceinline__ void gload_lds16(const void* g, void* l) {
  __builtin_amdgcn_global_load_lds((const __attribute__((address_space(1))) void*)g,
                                   (__attribute__((address_space(3))) void*)l, 16, 0, 0);
}

// Swizzled byte offset of frag granule (col c, k-granule kg) within one 8KB B tile.
__device__ __forceinline__ int bswz(int c, int kg) {
  return ((c >> 1) << 7) + (((((c & 1) << 2) | kg) ^ ((c >> 1) & 7)) << 4);
}

// ---------------- prep: combine ensemble -> ws (vectorized over k) ----------------
__global__ void prep_kernel(const float* __restrict__ fc_w, const float* __restrict__ fc_b,
                            const float* __restrict__ cls_w, const float* __restrict__ cls_b,
                            const float* __restrict__ factor, char* __restrict__ ws) {
  int tid = blockIdx.x * 256 + threadIdx.x;
  float f[N_ENS];
#pragma unroll
  for (int e = 0; e < N_ENS; ++e) f[e] = factor[e];

  if (tid < 25600) {                              // w1: 128 cols x 200 k-quads
    int col = tid / 200;
    int kq  = tid - col * 200;
    int k   = kq * 4;
    float4 v = float4{0.f, 0.f, 0.f, 0.f};
    if (k + 3 < D_IN) {
#pragma unroll
      for (int e = 0; e < N_ENS; ++e) {
        const float4 t = *(const float4*)(fc_w + (size_t)(e * D_HID + col) * D_IN + k);
        v.x += f[e] * t.x; v.y += f[e] * t.y; v.z += f[e] * t.z; v.w += f[e] * t.w;
      }
    }
    const int kt = k >> 5, kg = (k & 31) >> 3, half = k & 7;   // half in {0,4}
    union { unsigned short u[4]; uint2 p; } pk;
    pk.u[0] = f2bf(v.x); pk.u[1] = f2bf(v.y); pk.u[2] = f2bf(v.z); pk.u[3] = f2bf(v.w);
    *(uint2*)(ws + kt * TILE_B + bswz(col, kg) + half * 2) = pk.p;
  } else if (tid < 25600 + D_HID) {               // b1
    int col = tid - 25600;
    float v = 0.f;
#pragma unroll
    for (int e = 0; e < N_ENS; ++e) v += f[e] * fc_b[e * D_HID + col];
    *(float*)(ws + WS_B1 + col * 4) = v;
  } else if (tid < 25600 + D_HID + D_HID * D_OUT) {  // w2o[o][n]
    int i = tid - (25600 + D_HID);
    int o = i >> 7, n = i & 127;
    float v = 0.f;
#pragma unroll
    for (int e = 0; e < N_ENS; ++e) v += f[e] * cls_w[(e * D_OUT + o) * D_HID + n];
    *(float*)(ws + WS_W2 + i * 4) = v;
  } else if (tid < 25600 + D_HID + D_HID * D_OUT + D_OUT) {  // b2
    int o = tid - (25600 + D_HID + D_HID * D_OUT);
    float v = 0.f;
#pragma unroll
    for (int e = 0; e < N_ENS; ++e) v += f[e] * cls_b[e * D_OUT + o];
    *(float*)(ws + WS_B2 + o * 4) = v;
  }
}

// ---------------- main: contiguous-stream A to LDS, then K-loop ----------------
// BM=32, 2048 blocks, 256 thr (4 waves). 2 blocks/CU (LDS 76288 B).
// Phase 1: block's x-slice (contiguous 100KB of HBM) -> unit-stride float4 loads
//          -> bf16 A-LDS tile [32 rows][808] (stride 1616 B).
// Phase 2: R6-proven K-loop; wave w: cols w*32..+32 (2 ni), rows 0..31 (2 mi);
//          B via global_load_lds, 3 rotating bufs, counted vmcnt, 2 barriers/iter.
__global__ __launch_bounds__(256, 2) void mnist_fused(const float* __restrict__ x,
                                                      const char* __restrict__ ws,
                                                      float* __restrict__ out) {
  // LDS: A @0 (51712); B bufs @51712 (3x8192=24576) -> 76288 total.
  // Epilogue reuse: h f32 [32][132] @0; red @51712 (10240); w2s @61952 (5120).
  __shared__ __align__(16) char smem[76288];
  const int tid  = threadIdx.x;
  const int lane = tid & 63;
  const int w    = tid >> 6;
  const int l15  = lane & 15;
  const int kg   = lane >> 4;
  const int m0   = blockIdx.x * 32;

  char* Bb = smem + B_BASE;

  // ---- prologue: stage B(0)->buf0, B(1)->buf1 (before A phase so latency hides)
  gload_lds16(ws + w * 2048 + lane * 16,                 Bb + w * 2048);
  gload_lds16(ws + w * 2048 + 1024 + lane * 16,          Bb + w * 2048 + 1024);
  gload_lds16(ws + TILE_B + w * 2048 + lane * 16,        Bb + 8192 + w * 2048);
  gload_lds16(ws + TILE_B + w * 2048 + 1024 + lane * 16, Bb + 8192 + w * 2048 + 1024);

  // ---- phase 1: stage A (contiguous HBM stream -> bf16 LDS)
  // granule = 4 floats (16B read, 8B LDS write); 32 rows x 196 granules = 6272.
  {
    const float* xb = x + (size_t)m0 * D_IN;
#pragma unroll 6
    for (int i = 0; i < 24; ++i) {
      const int g   = i * 256 + tid;
      const int row = g / 196;
      const int c4  = g - row * 196;
      const float4 v = *(const float4*)(xb + row * D_IN + c4 * 4);
      union { unsigned short u[4]; uint2 p; } pk;
      pk.u[0] = f2bf(v.x); pk.u[1] = f2bf(v.y); pk.u[2] = f2bf(v.z); pk.u[3] = f2bf(v.w);
      *(uint2*)(smem + row * A_STRIDE + c4 * 8) = pk.p;
    }
    if (tid < 128) {   // tail: g = 6144+tid -> row 31, c4 = 68+tid
      const int c4 = 68 + tid;
      const float4 v = *(const float4*)(xb + 31 * D_IN + c4 * 4);
      union { unsigned short u[4]; uint2 p; } pk;
      pk.u[0] = f2bf(v.x); pk.u[1] = f2bf(v.y); pk.u[2] = f2bf(v.z); pk.u[3] = f2bf(v.w);
      *(uint2*)(smem + 31 * A_STRIDE + c4 * 8) = pk.p;
    }
    if (tid < 128) {   // zero-pad k = 784..799 (granules 196..199 of each row)
      const int row = tid >> 2, c4 = 196 + (tid & 3);
      *(uint2*)(smem + row * A_STRIDE + c4 * 8) = uint2{0u, 0u};
    }
  }
  __syncthreads();     // A tile + B(0),B(1) resident (drains vmcnt)

  // frag offsets
  int aoff[2];
#pragma unroll
  for (int mi = 0; mi < 2; ++mi) aoff[mi] = (mi * 16 + l15) * A_STRIDE + kg * 16;
  int boff[2];
#pragma unroll
  for (int ni = 0; ni < 2; ++ni) boff[ni] = bswz(w * 32 + ni * 16 + l15, kg);

  f32x4 acc[2][2];
#pragma unroll
  for (int mi = 0; mi < 2; ++mi)
#pragma unroll
    for (int ni = 0; ni < 2; ++ni) acc[mi][ni] = f32x4{0.f, 0.f, 0.f, 0.f};

  // ---- phase 2: K-loop (2-deep B prefetch, 3 bufs, counted vmcnt)
  int rdoff = 0, wroff = 16384;
  for (int kt = 0; kt < NKT; ++kt) {
    if (kt <= 22) {          // stage B(kt+2) into buf wroff
      const char* src = ws + (kt + 2) * TILE_B + w * 2048;
      char* dst = Bb + wroff + w * 2048;
      gload_lds16(src + lane * 16, dst);
      gload_lds16(src + 1024 + lane * 16, dst + 1024);
      SB; asm volatile("s_waitcnt vmcnt(4)" ::: "memory"); SB;
    } else if (kt == 23) {
      SB; asm volatile("s_waitcnt vmcnt(2)" ::: "memory"); SB;
    } else {
      SB; asm volatile("s_waitcnt vmcnt(0)" ::: "memory"); SB;
    }
    __builtin_amdgcn_s_barrier();   // B1: tile kt resident in buf rdoff
    SB;
    short8 a[2], b[2];
#pragma unroll
    for (int mi = 0; mi < 2; ++mi) a[mi] = *(const short8*)(smem + aoff[mi] + kt * 64);
#pragma unroll
    for (int ni = 0; ni < 2; ++ni) b[ni] = *(const short8*)(Bb + rdoff + boff[ni]);
#pragma unroll
    for (int mi = 0; mi < 2; ++mi)
#pragma unroll
      for (int ni = 0; ni < 2; ++ni)
        acc[mi][ni] = __builtin_amdgcn_mfma_f32_16x16x32_bf16(a[mi], b[ni], acc[mi][ni], 0, 0, 0);
    SB;
    __builtin_amdgcn_s_barrier();   // B2: buf rdoff consumed
    SB;
    rdoff = (rdoff == 16384) ? 0 : rdoff + 8192;
    wroff = (wroff == 16384) ? 0 : wroff + 8192;
  }

  __syncthreads();   // all A/B reads done; safe to reuse LDS

  // ---- epilogue 1: h = relu(acc + b1) -> LDS h[32][132]
  const float* b1g = (const float*)(ws + WS_B1);
  float (*h)[132] = (float (*)[132])smem;
#pragma unroll
  for (int ni = 0; ni < 2; ++ni) {
    const float bv = b1g[w * 32 + ni * 16 + l15];
#pragma unroll
    for (int mi = 0; mi < 2; ++mi) {
#pragma unroll
      for (int j = 0; j < 4; ++j) {
        float v = acc[mi][ni][j] + bv;
        h[mi * 16 + kg * 4 + j][w * 32 + ni * 16 + l15] = v > 0.f ? v : 0.f;
      }
    }
  }
  // stage w2 -> LDS (B region, disjoint from h)
  float* red = (float*)(smem + B_BASE);
  float* w2s = (float*)(smem + B_BASE + 10240);
  {
    const float* w2g = (const float*)(ws + WS_W2);
    for (int i = tid; i < 1280; i += 256) w2s[i] = w2g[i];
  }
  __syncthreads();

  // ---- epilogue 2: out = h @ w2^T + b2
  // thread (r = tid&31, q = tid>>5): 16 cols q*16..+16 of row r
  const int r = tid & 31, q = tid >> 5;
  float po[10];
#pragma unroll
  for (int o = 0; o < 10; ++o) po[o] = 0.f;
#pragma unroll
  for (int j4 = 0; j4 < 4; ++j4) {
    const float4 hv = *(const float4*)(&h[r][q * 16 + j4 * 4]);
#pragma unroll
    for (int o = 0; o < 10; ++o) {
      const float4 wv = *(const float4*)(w2s + o * 128 + q * 16 + j4 * 4);
      po[o] += hv.x * wv.x + hv.y * wv.y + hv.z * wv.z + hv.w * wv.w;
    }
  }
#pragma unroll
  for (int o = 0; o < 10; ++o) red[(q * 32 + r) * 10 + o] = po[o];
  __syncthreads();

  // 320 work items (32 rows x 10 outs) on 256 threads -> strided loop (R8 bug fix)
  for (int i = tid; i < 320; i += 256) {
    const int rr = i / 10, o = i - rr * 10;
    const float* b2g = (const float*)(ws + WS_B2);
    float s = b2g[o];
#pragma unroll
    for (int qq = 0; qq < 8; ++qq) s += red[(qq * 32 + rr) * 10 + o];
    out[(size_t)(m0 + rr) * 10 + o] = s;
  }
}

extern "C" void kernel_launch(void* const* d_in, const int* in_sizes, int n_in,
                              void* d_out, int out_size, void* d_ws, size_t ws_size,
                              hipStream_t stream) {
  const float* x      = (const float*)d_in[0];
  const float* fc_w   = (const float*)d_in[1];
  const float* fc_b   = (const float*)d_in[2];
  const float* cls_w  = (const float*)d_in[3];
  const float* cls_b  = (const float*)d_in[4];
  const float* factor = (const float*)d_in[5];
  char* ws = (char*)d_ws;
  float* outp = (float*)d_out;

  prep_kernel<<<106, 256, 0, stream>>>(fc_w, fc_b, cls_w, cls_b, factor, ws);
  mnist_fused<<<2048, 256, 0, stream>>>(x, ws, outp);
}